// Round 9
// baseline (274.657 us; speedup 1.0000x reference)
//
#include <hip/hip_runtime.h>

typedef unsigned short u16;
typedef __bf16 bf16x8 __attribute__((ext_vector_type(8)));
typedef float f32x4 __attribute__((ext_vector_type(4)));

#define SEQ   2048
#define DDIM  1024
#define EDIM  2048
#define FDIM  4224   /* 2E + S_ATT */
#define SATT  128
#define NBATCH 4

__device__ __forceinline__ u16 f2bf(float f) {
  unsigned u = __float_as_uint(f);
  unsigned r = (u + 0x7fffu + ((u >> 16) & 1u)) >> 16;
  return (u16)r;
}
__device__ __forceinline__ float bf2f(u16 v) {
  return __uint_as_float(((unsigned)v) << 16);
}

__device__ __forceinline__ void gload16(const u16* g, u16* l) {
  auto gp = (const __attribute__((address_space(1))) u16*)(unsigned long long)g;
  auto lp = (__attribute__((address_space(3))) u16*)(unsigned)(unsigned long long)l;
  __builtin_amdgcn_global_load_lds(gp, lp, 16, 0, 0);
}

// ---------------- elementwise / small kernels ----------------

__global__ void cvt_bf16_kernel(const float* __restrict__ in, u16* __restrict__ out, int n4) {
  int i = blockIdx.x * blockDim.x + threadIdx.x;
  if (i >= n4) return;
  float4 v = reinterpret_cast<const float4*>(in)[i];
  unsigned p0 = (unsigned)f2bf(v.x) | ((unsigned)f2bf(v.y) << 16);
  unsigned p1 = (unsigned)f2bf(v.z) | ((unsigned)f2bf(v.w) << 16);
  uint2 pk; pk.x = p0; pk.y = p1;
  reinterpret_cast<uint2*>(out)[i] = pk;
}

__global__ void rms_kernel(const float* __restrict__ x, const float* __restrict__ ln_g,
                           u16* __restrict__ xn) {
  int row = blockIdx.x;
  int t = threadIdx.x;
  const float4* xr = reinterpret_cast<const float4*>(x + (size_t)row * DDIM);
  float4 v = xr[t];
  float s = v.x * v.x + v.y * v.y + v.z * v.z + v.w * v.w;
#pragma unroll
  for (int off = 32; off > 0; off >>= 1) s += __shfl_down(s, off);
  __shared__ float wsum[4];
  int lane = t & 63, wv = t >> 6;
  if (lane == 0) wsum[wv] = s;
  __syncthreads();
  float tot = wsum[0] + wsum[1] + wsum[2] + wsum[3];
  float rms = sqrtf(tot * (1.0f / (float)DDIM));
  float scale = ln_g[0] / fmaxf(rms, 1e-5f);
  unsigned p0 = (unsigned)f2bf(v.x * scale) | ((unsigned)f2bf(v.y * scale) << 16);
  unsigned p1 = (unsigned)f2bf(v.z * scale) | ((unsigned)f2bf(v.w * scale) << 16);
  uint2 pk; pk.x = p0; pk.y = p1;
  reinterpret_cast<uint2*>(xn + (size_t)row * DDIM)[t] = pk;
}

__global__ void qk_kernel(const u16* __restrict__ uv, const float* __restrict__ pos_enc,
                          const float* __restrict__ gamma, const float* __restrict__ beta,
                          u16* __restrict__ q, u16* __restrict__ k, int ldF) {
  int r = blockIdx.x;
  int t = threadIdx.x;
  int s = r & (SEQ - 1);
  float bval = bf2f(uv[(size_t)r * ldF + 2 * EDIM + t]);
  float pe = pos_enc[(size_t)s * SATT + t];
  float qv = bval * gamma[t] + beta[t] + pe;
  float kv = bval * gamma[SATT + t] + beta[SATT + t] + pe;
  q[(size_t)r * SATT + t] = f2bf(qv);
  k[(size_t)r * SATT + t] = f2bf(kv);
}

// vt[b][e][s] = uv[b][s][E + e]
__global__ void transpose_v(const u16* __restrict__ uv, u16* __restrict__ vt, int ldF) {
  __shared__ u16 tile[32][33];
  int b = blockIdx.z;
  uv += (size_t)b * SEQ * ldF;
  vt += (size_t)b * EDIM * SEQ;
  int e0 = blockIdx.x * 32, s0 = blockIdx.y * 32;
  int tx = threadIdx.x, ty = threadIdx.y;
#pragma unroll
  for (int j = 0; j < 32; j += 8)
    tile[ty + j][tx] = uv[(size_t)(s0 + ty + j) * ldF + EDIM + e0 + tx];
  __syncthreads();
#pragma unroll
  for (int j = 0; j < 32; j += 8)
    vt[(size_t)(e0 + ty + j) * SEQ + s0 + tx] = tile[tx][ty + j];
}

// ======== gemm_sm: 128x128 tile, 2 blocks/CU, single-barrier dbuf ========
// C(M,N) = A(M,K)*B(N,K)^T. BK=64, 256 thr = 4 waves (2wr x 2wc), per-wave
// 64x64 via 4x4 frags of 16x16x32. LDS 64 KiB = 2 dbuf x (A[128][64] +
// B[128][64]). At tile t top: stage t+1 -> buf^1 (8 gload16/thread), then
// all 16 ds_read_b128 + 32 MFMA of tile t compiler-scheduled (no mid-tile
// barrier); boundary = vmcnt(0) + s_barrier + sched_barrier(0).
// Two independent blocks per CU cover each other's barrier/drain stalls
// (m114 mechanism). XOR swizzle byte^=(row&7)<<4 on ds_read; inverse
// pre-applied to the global staging source. NT = K/64 must be even.
template <int EPI>
__global__ __launch_bounds__(256, 2) void gemm_sm(
    const u16* __restrict__ A, const u16* __restrict__ B,
    int N, int K,
    u16* __restrict__ Cbf, float* __restrict__ Cf,
    const u16* __restrict__ U, int ldu,
    const float* __restrict__ Xres, const float* __restrict__ rscale,
    size_t sA, size_t sB, size_t sC, size_t sU) {
  __shared__ u16 lds[32768];  // 64 KiB
  const int tid = threadIdx.x;
  const int w = tid >> 6, l = tid & 63;
  const int wr = w >> 1, wc = w & 1;
  const int fr = l & 15, kg = l >> 4;

  const int bz = blockIdx.z;
  A += (size_t)bz * sA; B += (size_t)bz * sB; U += (size_t)bz * sU;

  // XCD-aware bijective swizzle (nwg % 8 == 0 for all launched shapes)
  const int nbx = gridDim.x;
  int li = blockIdx.y * nbx + blockIdx.x;
  const int cpx = (nbx * gridDim.y) >> 3;
  li = (li & 7) * cpx + (li >> 3);
  const int bn = li % nbx;
  const int bm = li / nbx;

  const int NT = K >> 6;  // even for all callers

  // staging: wave w, load L covers rows L*32 + w*8 + (l>>3); col pre-swizzled
  const int cswz = (((l & 7) ^ (l >> 3)) & 7) << 3;
  const u16* pA = A + (size_t)bm * 128 * K + (size_t)((w << 3) + (l >> 3)) * K + cswz;
  const u16* pB = B + (size_t)bn * 128 * K + (size_t)((w << 3) + (l >> 3)) * K + cswz;

  // precomputed swizzled LDS read bases (bytes)
  const int X  = (l & 7) << 4;
  const int Y0 = (kg << 4) ^ X;
  const int Y1 = ((kg << 4) | 64) ^ X;
  const char* ldsC = (const char*)lds;
  const char* aR0 = ldsC + wr * 8192 + fr * 128 + Y0;
  const char* aR1 = ldsC + wr * 8192 + fr * 128 + Y1;
  const char* bR0 = ldsC + 16384 + wc * 8192 + fr * 128 + Y0;
  const char* bR1 = ldsC + 16384 + wc * 8192 + fr * 128 + Y1;

  // stage one 128x64 panel (4 wave-loads); dst u16: buf*16384 + isB*8192
  auto stg = [&](int bufw, int isB, const u16* g, int ofs) {
    u16* base = lds + bufw * 16384 + isB * 8192 + w * 512;
#pragma unroll
    for (int L = 0; L < 4; L++)
      gload16(g + (size_t)(L * 32) * K + ofs, base + L * 2048);
  };

  f32x4 acc[4][4];
#pragma unroll
  for (int i = 0; i < 4; i++)
#pragma unroll
    for (int j = 0; j < 4; j++) acc[i][j] = f32x4{0.f, 0.f, 0.f, 0.f};

  // prologue: stage tile 0 -> buf0
  stg(0, 0, pA, 0); stg(0, 1, pB, 0);
  asm volatile("s_waitcnt vmcnt(0)" ::: "memory");
  __builtin_amdgcn_s_barrier();
  __builtin_amdgcn_sched_barrier(0);

  bf16x8 aH[4][2], bF[4][2];

#define TILE_STEP(BUF, ST, OFS)                                               \
  {                                                                           \
    if (ST) { stg((BUF) ^ 1, 0, pA, OFS); stg((BUF) ^ 1, 1, pB, OFS); }       \
    _Pragma("unroll") for (int i = 0; i < 4; i++) {                           \
      aH[i][0] = *(const bf16x8*)(aR0 + (BUF) * 32768 + i * 2048);            \
      aH[i][1] = *(const bf16x8*)(aR1 + (BUF) * 32768 + i * 2048);            \
    }                                                                         \
    _Pragma("unroll") for (int j = 0; j < 4; j++) {                           \
      bF[j][0] = *(const bf16x8*)(bR0 + (BUF) * 32768 + j * 2048);            \
      bF[j][1] = *(const bf16x8*)(bR1 + (BUF) * 32768 + j * 2048);            \
    }                                                                         \
    _Pragma("unroll") for (int s = 0; s < 2; s++)                             \
    _Pragma("unroll") for (int i = 0; i < 4; i++)                             \
    _Pragma("unroll") for (int j = 0; j < 4; j++)                             \
      acc[i][j] = __builtin_amdgcn_mfma_f32_16x16x32_bf16(                    \
          aH[i][s], bF[j][s], acc[i][j], 0, 0, 0);                            \
    asm volatile("s_waitcnt vmcnt(0)" ::: "memory");                          \
    __builtin_amdgcn_s_barrier();                                             \
    __builtin_amdgcn_sched_barrier(0);                                        \
  }

  for (int t2 = 0; t2 < NT; t2 += 2) {
    const bool st0 = (t2 + 1 < NT);
    const bool st1 = (t2 + 2 < NT);
    TILE_STEP(0, st0, 64)
    TILE_STEP(1, st1, 128)
    pA += 128; pB += 128;
  }
#undef TILE_STEP

  // epilogue
  const int m0 = bm * 128 + wr * 64;
  const int n0 = bn * 128 + wc * 64;
  const int rsub = (l >> 4) * 4;
  const int ccol = l & 15;
#pragma unroll
  for (int i = 0; i < 4; i++) {
#pragma unroll
    for (int j = 0; j < 4; j++) {
      int n = n0 + j * 16 + ccol;
#pragma unroll
      for (int tt = 0; tt < 4; tt++) {
        int m = m0 + i * 16 + rsub + tt;
        float v = acc[i][j][tt];
        size_t idx = (size_t)m * N + n;
        if constexpr (EPI == 0) {
          float sv = v / (1.f + __expf(-v));
          Cbf[(size_t)bz * sC + idx] = f2bf(sv);
        } else if constexpr (EPI == 1) {
          float sc = v * 0.08838834764831845f;  // 1/sqrt(128)
          sc = sc > 0.f ? sc * sc : 0.f;
          Cbf[(size_t)bz * sC + idx] = f2bf(sc);
        } else if constexpr (EPI == 2) {
          float uvl = bf2f(U[(size_t)m * ldu + n]);
          Cbf[(size_t)bz * sC + idx] = f2bf(v * uvl);
        } else {
          Cf[idx] = Xres[idx] * rscale[n] + v;
        }
      }
    }
  }
}

// ---------------- legacy 128x128 GEMM (fallback path only) ----------------
template <int EPI>
__global__ __launch_bounds__(256) void gemm_bt(
    const u16* __restrict__ A, const u16* __restrict__ B,
    int M, int N, int K,
    u16* __restrict__ Cbf, float* __restrict__ Cf,
    const u16* __restrict__ U, int ldu,
    const float* __restrict__ Xres, const float* __restrict__ rscale,
    size_t sA, size_t sB, size_t sC, size_t sU) {
  __shared__ u16 As[128 * 32];
  __shared__ u16 Bs[128 * 32];
  const int tid = threadIdx.x;
  const int wave = tid >> 6, lane = tid & 63;
  const int wr = wave >> 1, wc = wave & 1;
  const int bz = blockIdx.z;
  A += (size_t)bz * sA; B += (size_t)bz * sB; U += (size_t)bz * sU;
  const int nbx = gridDim.x;
  int li = blockIdx.y * nbx + blockIdx.x;
  const int cpx = (nbx * gridDim.y) >> 3;
  li = (li & 7) * cpx + (li >> 3);
  const int bn = li % nbx;
  const int bm = li / nbx;
  const size_t abase = (size_t)bm * 128 * K;
  const size_t bbase = (size_t)bn * 128 * K;
  const int srow = tid >> 2;
  const int scol = (tid & 3) * 8;
  f32x4 acc[4][4];
#pragma unroll
  for (int i = 0; i < 4; i++)
#pragma unroll
    for (int j = 0; j < 4; j++) acc[i][j] = f32x4{0.f, 0.f, 0.f, 0.f};
  const int fr = lane & 15;
  const int fk = (lane >> 4) * 8;
  for (int k0 = 0; k0 < K; k0 += 32) {
#pragma unroll
    for (int r = 0; r < 2; r++) {
      const u16* gA = A + abase + (size_t)(r * 64 + srow) * K + k0 + scol;
      const u16* gB = B + bbase + (size_t)(r * 64 + srow) * K + k0 + scol;
      gload16(gA, As + r * 2048 + wave * 512);
      gload16(gB, Bs + r * 2048 + wave * 512);
    }
    __syncthreads();
    bf16x8 af[4], bfr[4];
#pragma unroll
    for (int i = 0; i < 4; i++) {
      af[i]  = *reinterpret_cast<const bf16x8*>(&As[(wr * 64 + i * 16 + fr) * 32 + fk]);
      bfr[i] = *reinterpret_cast<const bf16x8*>(&Bs[(wc * 64 + i * 16 + fr) * 32 + fk]);
    }
#pragma unroll
    for (int i = 0; i < 4; i++)
#pragma unroll
      for (int j = 0; j < 4; j++)
        acc[i][j] = __builtin_amdgcn_mfma_f32_16x16x32_bf16(af[i], bfr[j], acc[i][j], 0, 0, 0);
    __syncthreads();
  }
  const int m0 = bm * 128 + wr * 64;
  const int n0 = bn * 128 + wc * 64;
  const int rsub = (lane >> 4) * 4;
  const int ccol = lane & 15;
#pragma unroll
  for (int i = 0; i < 4; i++) {
#pragma unroll
    for (int j = 0; j < 4; j++) {
      int n = n0 + j * 16 + ccol;
#pragma unroll
      for (int t = 0; t < 4; t++) {
        int m = m0 + i * 16 + rsub + t;
        float v = acc[i][j][t];
        size_t idx = (size_t)m * N + n;
        if constexpr (EPI == 0) {
          float sv = v / (1.f + __expf(-v));
          Cbf[(size_t)bz * sC + idx] = f2bf(sv);
        } else if constexpr (EPI == 1) {
          float sc = v * 0.08838834764831845f;
          sc = sc > 0.f ? sc * sc : 0.f;
          Cbf[(size_t)bz * sC + idx] = f2bf(sc);
        } else if constexpr (EPI == 2) {
          float uvl = bf2f(U[(size_t)m * ldu + n]);
          Cbf[(size_t)bz * sC + idx] = f2bf(v * uvl);
        } else {
          Cf[idx] = Xres[idx] * rscale[n] + v;
        }
      }
    }
  }
}

// ---------------- launcher ----------------

extern "C" void kernel_launch(void* const* d_in, const int* in_sizes, int n_in,
                              void* d_out, int out_size, void* d_ws, size_t ws_size,
                              hipStream_t stream) {
  const float* x        = (const float*)d_in[0];
  const float* pos_enc  = (const float*)d_in[1];
  const float* uv_w     = (const float*)d_in[2];
  const float* o_w      = (const float*)d_in[3];
  const float* gamma    = (const float*)d_in[4];
  const float* beta     = (const float*)d_in[5];
  const float* ln_g     = (const float*)d_in[6];
  const float* res_scale= (const float*)d_in[7];
  float* out = (float*)d_out;

  auto al = [](size_t b) { return (b + 255) & ~(size_t)255; };
  const size_t SZ_UVW  = (size_t)FDIM * DDIM * 2;
  const size_t SZ_OW   = (size_t)DDIM * EDIM * 2;
  const size_t SZ_Z    = (size_t)NBATCH * SEQ * EDIM * 2;
  const size_t SZ_XN   = (size_t)NBATCH * SEQ * DDIM * 2;
  const size_t SZ_UV   = (size_t)NBATCH * SEQ * FDIM * 2;
  const size_t SZ_QK   = (size_t)NBATCH * SEQ * SATT * 2;
  const size_t SZ_VT1  = (size_t)EDIM * SEQ * 2;
  const size_t SZ_P1   = (size_t)SEQ * SEQ * 2;
  const size_t need_full =
      al(SZ_UVW) + al(SZ_OW) + al(SZ_Z) + al(SZ_XN) + al(SZ_UV) + 2 * al(SZ_QK) +
      (size_t)NBATCH * (al(SZ_VT1) + al(SZ_P1));
  const bool FULL = ws_size >= need_full;

  char* p = (char*)d_ws;
  auto alloc = [&](size_t bytes) {
    char* r = p;
    p += (bytes + 255) & ~(size_t)255;
    return r;
  };

  if (FULL) {
    u16* uvw_bf = (u16*)alloc(SZ_UVW);
    u16* ow_bf  = (u16*)alloc(SZ_OW);
    u16* z      = (u16*)alloc(SZ_Z);
    u16* vt     = (u16*)alloc((size_t)NBATCH * al(SZ_VT1));
    u16* pmat   = (u16*)alloc((size_t)NBATCH * al(SZ_P1));
    u16* xn     = (u16*)alloc(SZ_XN);
    u16* uv     = (u16*)alloc(SZ_UV);
    u16* qb     = (u16*)alloc(SZ_QK);
    u16* kb     = (u16*)alloc(SZ_QK);
    const size_t sVT = al(SZ_VT1) >> 1;
    const size_t sP  = al(SZ_P1) >> 1;
    const int rows = NBATCH * SEQ;  // 8192

    cvt_bf16_kernel<<<(FDIM * DDIM / 4 + 255) / 256, 256, 0, stream>>>(
        uv_w, uvw_bf, FDIM * DDIM / 4);
    cvt_bf16_kernel<<<(DDIM * EDIM / 4 + 255) / 256, 256, 0, stream>>>(
        o_w, ow_bf, DDIM * EDIM / 4);

    rms_kernel<<<rows, 256, 0, stream>>>(x, ln_g, xn);
    // gemm0: 4224 = 33*128 exactly -> no ragged tiles; 2112 blocks
    gemm_sm<0><<<dim3(FDIM / 128, rows / 128), 256, 0, stream>>>(
        xn, uvw_bf, FDIM, DDIM, uv, nullptr, nullptr, 0, nullptr, nullptr,
        0, 0, 0, 0);
    qk_kernel<<<rows, SATT, 0, stream>>>(uv, pos_enc, gamma, beta, qb, kb, FDIM);
    transpose_v<<<dim3(EDIM / 32, SEQ / 32, NBATCH), dim3(32, 8), 0, stream>>>(uv, vt, FDIM);
    gemm_sm<1><<<dim3(SEQ / 128, SEQ / 128, NBATCH), 256, 0, stream>>>(
        qb, kb, SEQ, SATT, pmat, nullptr, nullptr, 0, nullptr, nullptr,
        (size_t)SEQ * SATT, (size_t)SEQ * SATT, sP, 0);
    gemm_sm<2><<<dim3(EDIM / 128, SEQ / 128, NBATCH), 256, 0, stream>>>(
        pmat, vt, EDIM, SEQ, z, nullptr, uv, FDIM, nullptr, nullptr,
        sP, sVT, (size_t)SEQ * EDIM, (size_t)SEQ * FDIM);
    gemm_sm<3><<<dim3(DDIM / 128, rows / 128), 256, 0, stream>>>(
        z, ow_bf, DDIM, EDIM, nullptr, out, nullptr, 0, x, res_scale,
        0, 0, 0, 0);
    return;
  }

  // ---------- fallback (small workspace): round-2 structure ----------
  u16* uvw_bf = (u16*)alloc(SZ_UVW);
  u16* ow_bf  = (u16*)alloc(SZ_OW);
  u16* z      = (u16*)alloc(SZ_Z);
  u16* vt     = (u16*)alloc(SZ_VT1);
  u16* pmat   = (u16*)alloc(SZ_P1);
  size_t fixed = (size_t)(p - (char*)d_ws);
  const size_t perbc = (size_t)SEQ * DDIM * 2 + (size_t)SEQ * FDIM * 2 +
                       2 * (size_t)SEQ * SATT * 2 + 4 * 256;
  int BC = (ws_size >= fixed + 4 * perbc) ? 4 : 1;
  u16* xn = (u16*)alloc((size_t)BC * SEQ * DDIM * 2);
  u16* uv = (u16*)alloc((size_t)BC * SEQ * FDIM * 2);
  u16* qb = (u16*)alloc((size_t)BC * SEQ * SATT * 2);
  u16* kb = (u16*)alloc((size_t)BC * SEQ * SATT * 2);

  cvt_bf16_kernel<<<(FDIM * DDIM / 4 + 255) / 256, 256, 0, stream>>>(
      uv_w, uvw_bf, FDIM * DDIM / 4);
  cvt_bf16_kernel<<<(DDIM * EDIM / 4 + 255) / 256, 256, 0, stream>>>(
      o_w, ow_bf, DDIM * EDIM / 4);

  for (int b0 = 0; b0 < NBATCH; b0 += BC) {
    int rows = BC * SEQ;
    rms_kernel<<<rows, 256, 0, stream>>>(x + (size_t)b0 * SEQ * DDIM, ln_g, xn);
    gemm_bt<0><<<dim3(FDIM / 128, rows / 128), 256, 0, stream>>>(
        xn, uvw_bf, rows, FDIM, DDIM, uv, nullptr, nullptr, 0, nullptr, nullptr,
        0, 0, 0, 0);
    qk_kernel<<<rows, SATT, 0, stream>>>(uv, pos_enc, gamma, beta, qb, kb, FDIM);
    for (int bb = 0; bb < BC; bb++) {
      int b = b0 + bb;
      const u16* uvb = uv + (size_t)bb * SEQ * FDIM;
      transpose_v<<<dim3(EDIM / 32, SEQ / 32, 1), dim3(32, 8), 0, stream>>>(uvb, vt, FDIM);
      gemm_bt<1><<<dim3(SEQ / 128, SEQ / 128), 256, 0, stream>>>(
          qb + (size_t)bb * SEQ * SATT, kb + (size_t)bb * SEQ * SATT,
          SEQ, SEQ, SATT, pmat, nullptr, nullptr, 0, nullptr, nullptr,
          0, 0, 0, 0);
      gemm_bt<2><<<dim3(EDIM / 128, SEQ / 128), 256, 0, stream>>>(
          pmat, vt, SEQ, EDIM, SEQ, z + (size_t)b * SEQ * EDIM, nullptr,
          uvb, FDIM, nullptr, nullptr, 0, 0, 0, 0);
    }
  }
  gemm_bt<3><<<dim3(DDIM / 128, (NBATCH * SEQ) / 128), 256, 0, stream>>>(
      z, ow_bf, NBATCH * SEQ, DDIM, EDIM, nullptr, out, nullptr, 0,
      x, res_scale, 0, 0, 0, 0);
}